// Round 3
// baseline (7783.138 us; speedup 1.0000x reference)
//
#include <hip/hip_runtime.h>
#include <stdint.h>

#define TT    512
#define HID   1024
#define G4    4096
#define INDIM 85
#define NOUT  20670   // 6890*3

typedef unsigned long long u64;

// ---------------------------------------------------------------------------
// Tiled fp32 GEMM: C[M,N] = A[M,K] * B[N,K]^T + bias0 + bias1
// 64x64 tile, BK=16, 256 threads, 4x4 micro-tile per thread.
// ---------------------------------------------------------------------------
__global__ __launch_bounds__(256)
void gemm_nt(const float* __restrict__ A, const float* __restrict__ B,
             const float* __restrict__ bias0, const float* __restrict__ bias1,
             float* __restrict__ C, int M, int N, int K)
{
    __shared__ float As[16 * 68];
    __shared__ float Bs[16 * 68];
    const int tid = threadIdx.x;
    const int tx = tid & 15, ty = tid >> 4;
    const int m0 = blockIdx.y * 64, n0 = blockIdx.x * 64;
    float acc[4][4] = {};
    const int KT = (K + 15) >> 4;

    for (int kt = 0; kt < KT; ++kt) {
        const int k0 = kt << 4;
        __syncthreads();
        for (int l = tid; l < 1024; l += 256) {
            const int mm = l >> 4, kk = l & 15;
            const int kg = k0 + kk;
            As[kk * 68 + mm] = (kg < K) ? A[(size_t)(m0 + mm) * K + kg] : 0.f;
            Bs[kk * 68 + mm] = (kg < K && (n0 + mm) < N)
                                   ? B[(size_t)(n0 + mm) * K + kg] : 0.f;
        }
        __syncthreads();
        #pragma unroll
        for (int kk = 0; kk < 16; ++kk) {
            const float4 av = *(const float4*)&As[kk * 68 + ty * 4];
            const float4 bv = *(const float4*)&Bs[kk * 68 + tx * 4];
            const float a[4] = {av.x, av.y, av.z, av.w};
            const float b[4] = {bv.x, bv.y, bv.z, bv.w};
            #pragma unroll
            for (int i = 0; i < 4; ++i)
                #pragma unroll
                for (int j = 0; j < 4; ++j)
                    acc[i][j] += a[i] * b[j];
        }
    }

    float bj[4];
    #pragma unroll
    for (int j = 0; j < 4; ++j) {
        const int n = n0 + tx * 4 + j;
        float bv = 0.f;
        if (n < N) {
            if (bias0) bv += bias0[n];
            if (bias1) bv += bias1[n];
        }
        bj[j] = bv;
    }
    #pragma unroll
    for (int i = 0; i < 4; ++i) {
        const int m = m0 + ty * 4 + i;
        #pragma unroll
        for (int j = 0; j < 4; ++j) {
            const int n = n0 + tx * 4 + j;
            if (n < N) C[(size_t)m * N + n] = acc[i][j] + bj[j];
        }
    }
}

// ---------------------------------------------------------------------------
// Fused 3-layer pipelined LSTM scan. 768 blocks x 256 threads.
//   layer = blockIdx>>8, b = blockIdx&255; block owns units u0=4b..4b+3.
// Wave w <-> gate w (4 rows). Dual mat-vec per step:
//   gates = W_ih * h_{l-1}[t]  (lanes 0..31)  +  W_hh * h_l[t-1] (lanes 32..63)
// Each lane: 4 rows x 32 cols of ONE matrix in registers (128 fp32/thread).
// Layer 0 uses precomputed x-gates (xg) instead of the W_ih half.
// h exchange via per-layer tagged u64 hbuf ((t+1)<<32 | f32bits), agent scope.
// Each thread's 4 tagged words come from ONE producer block (published
// together), so word 0 is a sentinel: poll it alone, then fetch the rest.
// __launch_bounds__(256,4): avoid the waves-per-eu=2 residency cap that kept
// layer 2 un-resident in round 2 (occupancy 20.6% == 2-blocks/CU phase story).
// ---------------------------------------------------------------------------
__device__ __forceinline__ float sig_(float x) { return 1.f / (1.f + expf(-x)); }

__global__ __launch_bounds__(256, 4)
void lstm_fused(const float* __restrict__ xg,
                const float* __restrict__ Whh0,
                const float* __restrict__ Wih1, const float* __restrict__ Whh1,
                const float* __restrict__ bih1, const float* __restrict__ bhh1,
                const float* __restrict__ Wih2, const float* __restrict__ Whh2,
                const float* __restrict__ bih2, const float* __restrict__ bhh2,
                u64* __restrict__ hbuf0, u64* __restrict__ hbuf1,
                u64* __restrict__ hbuf2, float* __restrict__ hs2)
{
    __shared__ float hin_lds[HID];
    __shared__ float hprev_lds[HID];
    __shared__ float gates[4][4];

    const int tid = threadIdx.x;
    const int w = tid >> 6, ln = tid & 63, q = ln & 31;
    const bool inHalf = (ln < 32);
    const int layer = blockIdx.x >> 8;
    const int b = blockIdx.x & 255;
    const int u0 = 4 * b;

    const float* Wih = (layer == 1) ? Wih1 : Wih2;                 // unused for layer 0
    const float* Whh = (layer == 0) ? Whh0 : (layer == 1 ? Whh1 : Whh2);
    u64* hbI = (layer == 1) ? hbuf0 : hbuf1;                        // input-h buffer (layers 1,2)
    u64* hbP = (layer == 0) ? hbuf0 : (layer == 1 ? hbuf1 : hbuf2); // own-layer buffer

    // ---- stage weights: 4 rows x 32 cols (lane-contiguous float4 chunks) ----
    float4 Wv[4][8];
    if (layer == 0 && inHalf) {
        #pragma unroll
        for (int rr = 0; rr < 4; ++rr)
            #pragma unroll
            for (int j = 0; j < 8; ++j)
                Wv[rr][j] = make_float4(0.f, 0.f, 0.f, 0.f);
    } else {
        const float* M = inHalf ? Wih : Whh;
        #pragma unroll
        for (int rr = 0; rr < 4; ++rr) {
            const float* rp = M + (size_t)(w * HID + u0 + rr) * HID + 4 * q;
            #pragma unroll
            for (int j = 0; j < 8; ++j)
                Wv[rr][j] = *(const float4*)(rp + 128 * j);
        }
    }

    // per-gate additive term on wave0 lanes 0..15 (lane = 4*gate + unit):
    //   layers 1,2: constant bias;   layer 0: reloaded from xg each step.
    float addv = 0.f;
    if (w == 0 && ln < 16 && layer > 0) {
        const int r = (ln >> 2) * HID + u0 + (ln & 3);
        addv = (layer == 1) ? (bih1[r] + bhh1[r]) : (bih2[r] + bhh2[r]);
    }

    if (layer == 0) {   // W_ih half unused: keep hin_lds at exact zeros
        const int p4z = 4 * ((tid + b) & 255);
        *(float4*)&hin_lds[p4z] = make_float4(0.f, 0.f, 0.f, 0.f);
    }

    float c = 0.f;   // cell state in wave-0 lanes 0..3
    for (int t = 0; t < TT; ++t) {
        if (layer == 0 && w == 0 && ln < 16)
            addv = xg[(size_t)t * G4 + (ln >> 2) * HID + u0 + (ln & 3)];

        // ---- acquire h vectors (block-rotated unit assignment) ----
        const int p4 = 4 * ((tid + b) & 255);
        bool doneP = (t == 0), doneI = (layer == 0);
        u64 vp0 = 0, vp1 = 0, vp2 = 0, vp3 = 0;
        u64 vi0 = 0, vi1 = 0, vi2 = 0, vi3 = 0;
        const u64 tagP = (u64)(unsigned)t;          // hbP[t-1] carries tag t
        const u64 tagI = (u64)(unsigned)(t + 1);    // hbI[t]   carries tag t+1
        const u64* pp = hbP + (size_t)(t - 1) * HID + p4;
        const u64* pi = hbI + (size_t)t * HID + p4;
        int guard = 0;
        for (;;) {
            if (!doneP) {
                vp0 = __hip_atomic_load(pp + 0, __ATOMIC_RELAXED, __HIP_MEMORY_SCOPE_AGENT);
                if ((vp0 >> 32) == tagP) {   // sentinel hit: rest published together
                    vp1 = __hip_atomic_load(pp + 1, __ATOMIC_RELAXED, __HIP_MEMORY_SCOPE_AGENT);
                    vp2 = __hip_atomic_load(pp + 2, __ATOMIC_RELAXED, __HIP_MEMORY_SCOPE_AGENT);
                    vp3 = __hip_atomic_load(pp + 3, __ATOMIC_RELAXED, __HIP_MEMORY_SCOPE_AGENT);
                    doneP = (vp1 >> 32) == tagP && (vp2 >> 32) == tagP &&
                            (vp3 >> 32) == tagP;
                }
            }
            if (!doneI) {
                vi0 = __hip_atomic_load(pi + 0, __ATOMIC_RELAXED, __HIP_MEMORY_SCOPE_AGENT);
                if ((vi0 >> 32) == tagI) {
                    vi1 = __hip_atomic_load(pi + 1, __ATOMIC_RELAXED, __HIP_MEMORY_SCOPE_AGENT);
                    vi2 = __hip_atomic_load(pi + 2, __ATOMIC_RELAXED, __HIP_MEMORY_SCOPE_AGENT);
                    vi3 = __hip_atomic_load(pi + 3, __ATOMIC_RELAXED, __HIP_MEMORY_SCOPE_AGENT);
                    doneI = (vi1 >> 32) == tagI && (vi2 >> 32) == tagI &&
                            (vi3 >> 32) == tagI;
                }
            }
            if (doneP && doneI) break;
            if (++guard > (1 << 22)) break;   // anti-hang bailout (unreached when healthy)
            __builtin_amdgcn_s_sleep(1);      // ~64 cy backoff: cut L3 poll pressure
        }
        if (t == 0)
            *(float4*)&hprev_lds[p4] = make_float4(0.f, 0.f, 0.f, 0.f);
        else
            *(float4*)&hprev_lds[p4] = make_float4(
                __uint_as_float((unsigned)vp0), __uint_as_float((unsigned)vp1),
                __uint_as_float((unsigned)vp2), __uint_as_float((unsigned)vp3));
        if (layer > 0)
            *(float4*)&hin_lds[p4] = make_float4(
                __uint_as_float((unsigned)vi0), __uint_as_float((unsigned)vi1),
                __uint_as_float((unsigned)vi2), __uint_as_float((unsigned)vi3));
        __syncthreads();   // (1) h vectors staged

        // ---- dual mat-vec: lane-contiguous float4 LDS reads, 128 FMA ----
        const float* hsrc = inHalf ? (hin_lds + 4 * q) : (hprev_lds + 4 * q);
        float a0 = 0.f, a1 = 0.f, a2 = 0.f, a3 = 0.f;
        #pragma unroll
        for (int j = 0; j < 8; ++j) {
            const float4 hv = *(const float4*)(hsrc + 128 * j);
            a0 += Wv[0][j].x * hv.x + Wv[0][j].y * hv.y + Wv[0][j].z * hv.z + Wv[0][j].w * hv.w;
            a1 += Wv[1][j].x * hv.x + Wv[1][j].y * hv.y + Wv[1][j].z * hv.z + Wv[1][j].w * hv.w;
            a2 += Wv[2][j].x * hv.x + Wv[2][j].y * hv.y + Wv[2][j].z * hv.z + Wv[2][j].w * hv.w;
            a3 += Wv[3][j].x * hv.x + Wv[3][j].y * hv.y + Wv[3][j].z * hv.z + Wv[3][j].w * hv.w;
        }
        #pragma unroll
        for (int off = 1; off < 64; off <<= 1) {
            a0 += __shfl_xor(a0, off, 64);
            a1 += __shfl_xor(a1, off, 64);
            a2 += __shfl_xor(a2, off, 64);
            a3 += __shfl_xor(a3, off, 64);
        }
        if (ln == 0) {
            gates[w][0] = a0; gates[w][1] = a1; gates[w][2] = a2; gates[w][3] = a3;
        }
        __syncthreads();   // (2) gate sums exchanged

        // ---- wave 0: elementwise + publish ----
        if (w == 0) {
            const int uu = ln & 3;
            const float xi = __shfl(addv, uu, 64);
            const float xf = __shfl(addv, 4 + uu, 64);
            const float xgv = __shfl(addv, 8 + uu, 64);
            const float xo = __shfl(addv, 12 + uu, 64);
            if (ln < 4) {
                const float i_ = sig_(gates[0][ln] + xi);
                const float f_ = sig_(gates[1][ln] + xf);
                const float g_ = tanhf(gates[2][ln] + xgv);
                const float o_ = sig_(gates[3][ln] + xo);
                c = f_ * c + i_ * g_;
                const float h = o_ * tanhf(c);
                if (layer == 2) hs2[(size_t)t * HID + u0 + ln] = h;
                const u64 pv = (((u64)(unsigned)(t + 1)) << 32) |
                               (u64)__float_as_uint(h);
                __hip_atomic_store(hbP + (size_t)t * HID + u0 + ln, pv,
                                   __ATOMIC_RELAXED, __HIP_MEMORY_SCOPE_AGENT);
            }
        }
    }
}

// ---------------------------------------------------------------------------
extern "C" void kernel_launch(void* const* d_in, const int* in_sizes, int n_in,
                              void* d_out, int out_size, void* d_ws, size_t ws_size,
                              hipStream_t stream)
{
    (void)in_sizes; (void)n_in; (void)out_size; (void)ws_size;

    const float* pose = (const float*)d_in[0];
    const float* Wih0 = (const float*)d_in[1];
    const float* Whh0 = (const float*)d_in[2];
    const float* bih0 = (const float*)d_in[3];
    const float* bhh0 = (const float*)d_in[4];
    const float* Wih1 = (const float*)d_in[5];
    const float* Whh1 = (const float*)d_in[6];
    const float* bih1 = (const float*)d_in[7];
    const float* bhh1 = (const float*)d_in[8];
    const float* Wih2 = (const float*)d_in[9];
    const float* Whh2 = (const float*)d_in[10];
    const float* bih2 = (const float*)d_in[11];
    const float* bhh2 = (const float*)d_in[12];
    const float* Wout = (const float*)d_in[13];
    float* out = (float*)d_out;

    // Workspace: hbuf0|hbuf1|hbuf2 (3 x 4 MB tagged u64) | xg (8 MB) | hs2 (2 MB)
    char* ws = (char*)d_ws;
    const size_t HB = (size_t)TT * HID * sizeof(u64);
    u64* hbuf0 = (u64*)ws;
    u64* hbuf1 = (u64*)(ws + HB);
    u64* hbuf2 = (u64*)(ws + 2 * HB);
    float* xg  = (float*)(ws + 3 * HB);
    float* hs2 = (float*)(ws + 3 * HB + (size_t)TT * G4 * sizeof(float));

    hipMemsetAsync(hbuf0, 0, 3 * HB, stream);

    const dim3 blk(256);
    // layer-0 x-gates: [512,85] x [85,4096]^T (+ both biases)
    gemm_nt<<<dim3(G4 / 64, TT / 64), blk, 0, stream>>>(
        pose, Wih0, bih0, bhh0, xg, TT, G4, INDIM);
    // fused pipelined 3-layer scan
    lstm_fused<<<dim3(768), blk, 0, stream>>>(
        xg, Whh0, Wih1, Whh1, bih1, bhh1, Wih2, Whh2, bih2, bhh2,
        hbuf0, hbuf1, hbuf2, hs2);
    // output projection: [512,1024] x [1024,20670]^T
    gemm_nt<<<dim3((NOUT + 63) / 64, TT / 64), blk, 0, stream>>>(
        hs2, Wout, nullptr, nullptr, out, TT, NOUT, HID);
}

// Round 4
// 5782.367 us; speedup vs baseline: 1.3460x; 1.3460x over previous
//
#include <hip/hip_runtime.h>
#include <stdint.h>

#define TT    512
#define HID   1024
#define G4    4096
#define INDIM 85
#define NOUT  20670   // 6890*3

typedef unsigned long long u64;

// ---------------------------------------------------------------------------
// Tiled fp32 GEMM: C[M,N] = A[M,K] * B[N,K]^T + bias0 + bias1
// 64x64 tile, BK=16, 256 threads, 4x4 micro-tile per thread.
// ---------------------------------------------------------------------------
__global__ __launch_bounds__(256)
void gemm_nt(const float* __restrict__ A, const float* __restrict__ B,
             const float* __restrict__ bias0, const float* __restrict__ bias1,
             float* __restrict__ C, int M, int N, int K)
{
    __shared__ float As[16 * 68];
    __shared__ float Bs[16 * 68];
    const int tid = threadIdx.x;
    const int tx = tid & 15, ty = tid >> 4;
    const int m0 = blockIdx.y * 64, n0 = blockIdx.x * 64;
    float acc[4][4] = {};
    const int KT = (K + 15) >> 4;

    for (int kt = 0; kt < KT; ++kt) {
        const int k0 = kt << 4;
        __syncthreads();
        for (int l = tid; l < 1024; l += 256) {
            const int mm = l >> 4, kk = l & 15;
            const int kg = k0 + kk;
            As[kk * 68 + mm] = (kg < K) ? A[(size_t)(m0 + mm) * K + kg] : 0.f;
            Bs[kk * 68 + mm] = (kg < K && (n0 + mm) < N)
                                   ? B[(size_t)(n0 + mm) * K + kg] : 0.f;
        }
        __syncthreads();
        #pragma unroll
        for (int kk = 0; kk < 16; ++kk) {
            const float4 av = *(const float4*)&As[kk * 68 + ty * 4];
            const float4 bv = *(const float4*)&Bs[kk * 68 + tx * 4];
            const float a[4] = {av.x, av.y, av.z, av.w};
            const float b[4] = {bv.x, bv.y, bv.z, bv.w};
            #pragma unroll
            for (int i = 0; i < 4; ++i)
                #pragma unroll
                for (int j = 0; j < 4; ++j)
                    acc[i][j] += a[i] * b[j];
        }
    }

    float bj[4];
    #pragma unroll
    for (int j = 0; j < 4; ++j) {
        const int n = n0 + tx * 4 + j;
        float bv = 0.f;
        if (n < N) {
            if (bias0) bv += bias0[n];
            if (bias1) bv += bias1[n];
        }
        bj[j] = bv;
    }
    #pragma unroll
    for (int i = 0; i < 4; ++i) {
        const int m = m0 + ty * 4 + i;
        #pragma unroll
        for (int j = 0; j < 4; ++j) {
            const int n = n0 + tx * 4 + j;
            if (n < N) C[(size_t)m * N + n] = acc[i][j] + bj[j];
        }
    }
}

// ---------------------------------------------------------------------------
// Fused 3-layer pipelined LSTM scan. 768 blocks x 256 threads.
//   layer = blockIdx>>8, b = blockIdx&255; block owns units u0=4b..4b+3.
// NEW mapping: wave w owns unit (u0+w) and ALL 4 of its gates.
//   lanes 0..31:  W_ih rows {g*1024+unit}, 32 cols/lane   (layer 0: zeros)
//   lanes 32..63: W_hh rows {g*1024+unit}, 32 cols/lane
// 64-lane butterfly sums ih+hh partials -> full gate value on every lane;
// lane 0 does the elementwise + PUBLISHES BEFORE the LDS-reuse barrier, so
// the inter-block critical path is poll -> matvec -> reduce -> publish.
// __launch_bounds__(256,3): reg cap 170 = 128 weight regs fit (round 3's
// cap of 128 spilled weights to scratch -> 12.4 GB refetch), and 3 blocks/CU
// keeps all 768 blocks co-resident.
// h exchange via per-layer tagged u64 hbuf ((t+1)<<32 | f32bits), agent scope,
// sentinel-word poll. Deps point only to lower blockIdx -> deadlock-free.
// ---------------------------------------------------------------------------
__device__ __forceinline__ float sig_(float x) { return 1.f / (1.f + expf(-x)); }

__global__ __launch_bounds__(256, 3)
void lstm_fused(const float* __restrict__ xg,
                const float* __restrict__ Whh0,
                const float* __restrict__ Wih1, const float* __restrict__ Whh1,
                const float* __restrict__ bih1, const float* __restrict__ bhh1,
                const float* __restrict__ Wih2, const float* __restrict__ Whh2,
                const float* __restrict__ bih2, const float* __restrict__ bhh2,
                u64* __restrict__ hbuf0, u64* __restrict__ hbuf1,
                u64* __restrict__ hbuf2, float* __restrict__ hs2)
{
    __shared__ float hin_lds[HID];
    __shared__ float hprev_lds[HID];

    const int tid = threadIdx.x;
    const int w = tid >> 6, ln = tid & 63, q = ln & 31;
    const bool inHalf = (ln < 32);
    const int layer = blockIdx.x >> 8;
    const int b = blockIdx.x & 255;
    const int unit = 4 * b + w;

    const float* Wih = (layer == 1) ? Wih1 : Wih2;                 // unused for layer 0
    const float* Whh = (layer == 0) ? Whh0 : (layer == 1 ? Whh1 : Whh2);
    u64* hbI = (layer == 1) ? hbuf0 : hbuf1;                        // input-h buffer (layers 1,2)
    u64* hbP = (layer == 0) ? hbuf0 : (layer == 1 ? hbuf1 : hbuf2); // own-layer buffer

    // ---- stage weights: 4 gate-rows x 32 cols of one matrix per lane ----
    float4 Wv[4][8];
    if (layer == 0 && inHalf) {
        #pragma unroll
        for (int g = 0; g < 4; ++g)
            #pragma unroll
            for (int j = 0; j < 8; ++j)
                Wv[g][j] = make_float4(0.f, 0.f, 0.f, 0.f);
    } else {
        const float* M = inHalf ? Wih : Whh;
        #pragma unroll
        for (int g = 0; g < 4; ++g) {
            const float* rp = M + (size_t)(g * HID + unit) * HID + 4 * q;
            #pragma unroll
            for (int j = 0; j < 8; ++j)
                Wv[g][j] = *(const float4*)(rp + 128 * j);
        }
    }

    // per-gate additive term for this wave's unit, lane 0 only.
    float add4[4] = {0.f, 0.f, 0.f, 0.f};
    if (ln == 0 && layer > 0) {
        #pragma unroll
        for (int g = 0; g < 4; ++g) {
            const int r = g * HID + unit;
            add4[g] = (layer == 1) ? (bih1[r] + bhh1[r]) : (bih2[r] + bhh2[r]);
        }
    }

    if (layer == 0) {   // W_ih half unused: keep hin_lds at exact zeros
        const int p4z = 4 * ((tid + b) & 255);
        *(float4*)&hin_lds[p4z] = make_float4(0.f, 0.f, 0.f, 0.f);
    }

    float c = 0.f;   // cell state in lane 0 of each wave
    for (int t = 0; t < TT; ++t) {
        if (layer == 0 && ln == 0) {   // x-gates for this unit (prefetch pre-poll)
            #pragma unroll
            for (int g = 0; g < 4; ++g)
                add4[g] = xg[(size_t)t * G4 + g * HID + unit];
        }

        // ---- acquire h vectors (block-rotated unit assignment) ----
        const int p4 = 4 * ((tid + b) & 255);
        bool doneP = (t == 0), doneI = (layer == 0);
        u64 vp0 = 0, vp1 = 0, vp2 = 0, vp3 = 0;
        u64 vi0 = 0, vi1 = 0, vi2 = 0, vi3 = 0;
        const u64 tagP = (u64)(unsigned)t;          // hbP[t-1] carries tag t
        const u64 tagI = (u64)(unsigned)(t + 1);    // hbI[t]   carries tag t+1
        const u64* pp = hbP + (size_t)(t - 1) * HID + p4;
        const u64* pi = hbI + (size_t)t * HID + p4;
        int guard = 0;
        for (;;) {
            if (!doneP) {
                vp0 = __hip_atomic_load(pp + 0, __ATOMIC_RELAXED, __HIP_MEMORY_SCOPE_AGENT);
                if ((vp0 >> 32) == tagP) {   // sentinel hit: rest published together
                    vp1 = __hip_atomic_load(pp + 1, __ATOMIC_RELAXED, __HIP_MEMORY_SCOPE_AGENT);
                    vp2 = __hip_atomic_load(pp + 2, __ATOMIC_RELAXED, __HIP_MEMORY_SCOPE_AGENT);
                    vp3 = __hip_atomic_load(pp + 3, __ATOMIC_RELAXED, __HIP_MEMORY_SCOPE_AGENT);
                    doneP = (vp1 >> 32) == tagP && (vp2 >> 32) == tagP &&
                            (vp3 >> 32) == tagP;
                }
            }
            if (!doneI) {
                vi0 = __hip_atomic_load(pi + 0, __ATOMIC_RELAXED, __HIP_MEMORY_SCOPE_AGENT);
                if ((vi0 >> 32) == tagI) {
                    vi1 = __hip_atomic_load(pi + 1, __ATOMIC_RELAXED, __HIP_MEMORY_SCOPE_AGENT);
                    vi2 = __hip_atomic_load(pi + 2, __ATOMIC_RELAXED, __HIP_MEMORY_SCOPE_AGENT);
                    vi3 = __hip_atomic_load(pi + 3, __ATOMIC_RELAXED, __HIP_MEMORY_SCOPE_AGENT);
                    doneI = (vi1 >> 32) == tagI && (vi2 >> 32) == tagI &&
                            (vi3 >> 32) == tagI;
                }
            }
            if (doneP && doneI) break;
            if (++guard > (1 << 22)) break;   // anti-hang bailout (unreached when healthy)
        }
        if (t == 0)
            *(float4*)&hprev_lds[p4] = make_float4(0.f, 0.f, 0.f, 0.f);
        else
            *(float4*)&hprev_lds[p4] = make_float4(
                __uint_as_float((unsigned)vp0), __uint_as_float((unsigned)vp1),
                __uint_as_float((unsigned)vp2), __uint_as_float((unsigned)vp3));
        if (layer > 0)
            *(float4*)&hin_lds[p4] = make_float4(
                __uint_as_float((unsigned)vi0), __uint_as_float((unsigned)vi1),
                __uint_as_float((unsigned)vi2), __uint_as_float((unsigned)vi3));
        __syncthreads();   // (1) h vectors staged

        // ---- matvec: 4 gate rows x 32 cols, weights in regs, h from LDS ----
        const float* hsrc = (inHalf ? hin_lds : hprev_lds) + 4 * q;
        float a0 = 0.f, a1 = 0.f, a2 = 0.f, a3 = 0.f;
        #pragma unroll
        for (int j = 0; j < 8; ++j) {
            const float4 hv = *(const float4*)(hsrc + 128 * j);
            a0 += Wv[0][j].x * hv.x + Wv[0][j].y * hv.y + Wv[0][j].z * hv.z + Wv[0][j].w * hv.w;
            a1 += Wv[1][j].x * hv.x + Wv[1][j].y * hv.y + Wv[1][j].z * hv.z + Wv[1][j].w * hv.w;
            a2 += Wv[2][j].x * hv.x + Wv[2][j].y * hv.y + Wv[2][j].z * hv.z + Wv[2][j].w * hv.w;
            a3 += Wv[3][j].x * hv.x + Wv[3][j].y * hv.y + Wv[3][j].z * hv.z + Wv[3][j].w * hv.w;
        }
        // 64-lane butterfly: sums ih-partials (lanes<32) + hh-partials (>=32)
        #pragma unroll
        for (int off = 1; off < 64; off <<= 1) {
            a0 += __shfl_xor(a0, off, 64);
            a1 += __shfl_xor(a1, off, 64);
            a2 += __shfl_xor(a2, off, 64);
            a3 += __shfl_xor(a3, off, 64);
        }

        // ---- lane 0: elementwise + publish (BEFORE the reuse barrier) ----
        if (ln == 0) {
            const float i_ = sig_(a0 + add4[0]);
            const float f_ = sig_(a1 + add4[1]);
            const float g_ = tanhf(a2 + add4[2]);
            const float o_ = sig_(a3 + add4[3]);
            c = f_ * c + i_ * g_;
            const float h = o_ * tanhf(c);
            if (layer == 2) hs2[(size_t)t * HID + unit] = h;
            const u64 pv = (((u64)(unsigned)(t + 1)) << 32) |
                           (u64)__float_as_uint(h);
            __hip_atomic_store(hbP + (size_t)t * HID + unit, pv,
                               __ATOMIC_RELAXED, __HIP_MEMORY_SCOPE_AGENT);
        }
        __syncthreads();   // (2) all reads done -> next iter may overwrite LDS
    }
}

// ---------------------------------------------------------------------------
extern "C" void kernel_launch(void* const* d_in, const int* in_sizes, int n_in,
                              void* d_out, int out_size, void* d_ws, size_t ws_size,
                              hipStream_t stream)
{
    (void)in_sizes; (void)n_in; (void)out_size; (void)ws_size;

    const float* pose = (const float*)d_in[0];
    const float* Wih0 = (const float*)d_in[1];
    const float* Whh0 = (const float*)d_in[2];
    const float* bih0 = (const float*)d_in[3];
    const float* bhh0 = (const float*)d_in[4];
    const float* Wih1 = (const float*)d_in[5];
    const float* Whh1 = (const float*)d_in[6];
    const float* bih1 = (const float*)d_in[7];
    const float* bhh1 = (const float*)d_in[8];
    const float* Wih2 = (const float*)d_in[9];
    const float* Whh2 = (const float*)d_in[10];
    const float* bih2 = (const float*)d_in[11];
    const float* bhh2 = (const float*)d_in[12];
    const float* Wout = (const float*)d_in[13];
    float* out = (float*)d_out;

    // Workspace: hbuf0|hbuf1|hbuf2 (3 x 4 MB tagged u64) | xg (8 MB) | hs2 (2 MB)
    char* ws = (char*)d_ws;
    const size_t HB = (size_t)TT * HID * sizeof(u64);
    u64* hbuf0 = (u64*)ws;
    u64* hbuf1 = (u64*)(ws + HB);
    u64* hbuf2 = (u64*)(ws + 2 * HB);
    float* xg  = (float*)(ws + 3 * HB);
    float* hs2 = (float*)(ws + 3 * HB + (size_t)TT * G4 * sizeof(float));

    hipMemsetAsync(hbuf0, 0, 3 * HB, stream);

    const dim3 blk(256);
    // layer-0 x-gates: [512,85] x [85,4096]^T (+ both biases)
    gemm_nt<<<dim3(G4 / 64, TT / 64), blk, 0, stream>>>(
        pose, Wih0, bih0, bhh0, xg, TT, G4, INDIM);
    // fused pipelined 3-layer scan
    lstm_fused<<<dim3(768), blk, 0, stream>>>(
        xg, Whh0, Wih1, Whh1, bih1, bhh1, Wih2, Whh2, bih2, bhh2,
        hbuf0, hbuf1, hbuf2, hs2);
    // output projection: [512,1024] x [1024,20670]^T
    gemm_nt<<<dim3((NOUT + 63) / 64, TT / 64), blk, 0, stream>>>(
        hs2, Wout, nullptr, nullptr, out, TT, NOUT, HID);
}

// Round 5
// 4737.390 us; speedup vs baseline: 1.6429x; 1.2206x over previous
//
#include <hip/hip_runtime.h>
#include <stdint.h>

#define TT    512
#define HID   1024
#define G4    4096
#define INDIM 85
#define NOUT  20670   // 6890*3

typedef unsigned long long u64;

// ---------------------------------------------------------------------------
// Tiled fp32 GEMM: C[M,N] = A[M,K] * B[N,K]^T + bias0 + bias1
// 64x64 tile, BK=16, 256 threads, 4x4 micro-tile per thread.
// ---------------------------------------------------------------------------
__global__ __launch_bounds__(256)
void gemm_nt(const float* __restrict__ A, const float* __restrict__ B,
             const float* __restrict__ bias0, const float* __restrict__ bias1,
             float* __restrict__ C, int M, int N, int K)
{
    __shared__ float As[16 * 68];
    __shared__ float Bs[16 * 68];
    const int tid = threadIdx.x;
    const int tx = tid & 15, ty = tid >> 4;
    const int m0 = blockIdx.y * 64, n0 = blockIdx.x * 64;
    float acc[4][4] = {};
    const int KT = (K + 15) >> 4;

    for (int kt = 0; kt < KT; ++kt) {
        const int k0 = kt << 4;
        __syncthreads();
        for (int l = tid; l < 1024; l += 256) {
            const int mm = l >> 4, kk = l & 15;
            const int kg = k0 + kk;
            As[kk * 68 + mm] = (kg < K) ? A[(size_t)(m0 + mm) * K + kg] : 0.f;
            Bs[kk * 68 + mm] = (kg < K && (n0 + mm) < N)
                                   ? B[(size_t)(n0 + mm) * K + kg] : 0.f;
        }
        __syncthreads();
        #pragma unroll
        for (int kk = 0; kk < 16; ++kk) {
            const float4 av = *(const float4*)&As[kk * 68 + ty * 4];
            const float4 bv = *(const float4*)&Bs[kk * 68 + tx * 4];
            const float a[4] = {av.x, av.y, av.z, av.w};
            const float b[4] = {bv.x, bv.y, bv.z, bv.w};
            #pragma unroll
            for (int i = 0; i < 4; ++i)
                #pragma unroll
                for (int j = 0; j < 4; ++j)
                    acc[i][j] += a[i] * b[j];
        }
    }

    float bj[4];
    #pragma unroll
    for (int j = 0; j < 4; ++j) {
        const int n = n0 + tx * 4 + j;
        float bv = 0.f;
        if (n < N) {
            if (bias0) bv += bias0[n];
            if (bias1) bv += bias1[n];
        }
        bj[j] = bv;
    }
    #pragma unroll
    for (int i = 0; i < 4; ++i) {
        const int m = m0 + ty * 4 + i;
        #pragma unroll
        for (int j = 0; j < 4; ++j) {
            const int n = n0 + tx * 4 + j;
            if (n < N) C[(size_t)m * N + n] = acc[i][j] + bj[j];
        }
    }
}

// ---------------------------------------------------------------------------
// Fused 3-layer pipelined LSTM scan. 768 blocks x 256 threads.
//   layer = blockIdx>>8, b = blockIdx&255; block owns units u0=4b..4b+3.
// Compute mapping: wave w owns unit (u0+w) and ALL 4 of its gates:
//   lanes 0..31:  W_ih rows, 32 cols/lane (layer 0: zeros)
//   lanes 32..63: W_hh rows, 32 cols/lane
// 64-lane butterfly sums ih+hh partials; lane 0 drops the 4 gate sums in
// gsum[w][*]. After barrier(2), WAVE 0 LANES 0..3 do the elementwise for all
// 4 units and publish the 4 tagged u64s from ADJACENT LANES — one coalesced
// store, simultaneous L3 arrival. (Round 4 published from lane0 of 4
// different waves; the inter-wave skew made consumers spin on words 1..3
// after the sentinel hit — the 10us/slot regression.)
// h exchange via per-layer tagged u64 hbuf ((t+1)<<32 | f32bits), agent
// scope, sentinel-word poll + s_sleep backoff. Deps point only to lower
// blockIdx -> deadlock-free under partial residency.
// __launch_bounds__(256,3): reg cap 170 fits the 128 weight regs (cap 128
// spilled them -> 12.4 GB refetch in round 3) at 3 blocks/CU residency.
// ---------------------------------------------------------------------------
__device__ __forceinline__ float sig_(float x) { return 1.f / (1.f + expf(-x)); }

__global__ __launch_bounds__(256, 3)
void lstm_fused(const float* __restrict__ xg,
                const float* __restrict__ Whh0,
                const float* __restrict__ Wih1, const float* __restrict__ Whh1,
                const float* __restrict__ bih1, const float* __restrict__ bhh1,
                const float* __restrict__ Wih2, const float* __restrict__ Whh2,
                const float* __restrict__ bih2, const float* __restrict__ bhh2,
                u64* __restrict__ hbuf0, u64* __restrict__ hbuf1,
                u64* __restrict__ hbuf2, float* __restrict__ hs2)
{
    __shared__ float hin_lds[HID];
    __shared__ float hprev_lds[HID];
    __shared__ float gsum[4][4];   // [wave/unit][gate]

    const int tid = threadIdx.x;
    const int w = tid >> 6, ln = tid & 63, q = ln & 31;
    const bool inHalf = (ln < 32);
    const int layer = blockIdx.x >> 8;
    const int b = blockIdx.x & 255;
    const int u0 = 4 * b;
    const int unit = u0 + w;

    const float* Wih = (layer == 1) ? Wih1 : Wih2;                 // unused for layer 0
    const float* Whh = (layer == 0) ? Whh0 : (layer == 1 ? Whh1 : Whh2);
    u64* hbI = (layer == 1) ? hbuf0 : hbuf1;                        // input-h buffer (layers 1,2)
    u64* hbP = (layer == 0) ? hbuf0 : (layer == 1 ? hbuf1 : hbuf2); // own-layer buffer

    // ---- stage weights: 4 gate-rows x 32 cols of one matrix per lane ----
    float4 Wv[4][8];
    if (layer == 0 && inHalf) {
        #pragma unroll
        for (int g = 0; g < 4; ++g)
            #pragma unroll
            for (int j = 0; j < 8; ++j)
                Wv[g][j] = make_float4(0.f, 0.f, 0.f, 0.f);
    } else {
        const float* M = inHalf ? Wih : Whh;
        #pragma unroll
        for (int g = 0; g < 4; ++g) {
            const float* rp = M + (size_t)(g * HID + unit) * HID + 4 * q;
            #pragma unroll
            for (int j = 0; j < 8; ++j)
                Wv[g][j] = *(const float4*)(rp + 128 * j);
        }
    }

    // per-gate additive term: WAVE 0 LANES 0..3, lane ln handles unit u0+ln.
    float add4[4] = {0.f, 0.f, 0.f, 0.f};
    if (w == 0 && ln < 4 && layer > 0) {
        #pragma unroll
        for (int g = 0; g < 4; ++g) {
            const int r = g * HID + u0 + ln;
            add4[g] = (layer == 1) ? (bih1[r] + bhh1[r]) : (bih2[r] + bhh2[r]);
        }
    }

    if (layer == 0) {   // W_ih half unused: keep hin_lds at exact zeros
        const int p4z = 4 * ((tid + b) & 255);
        *(float4*)&hin_lds[p4z] = make_float4(0.f, 0.f, 0.f, 0.f);
    }

    float c = 0.f;   // cell state in wave-0 lanes 0..3
    for (int t = 0; t < TT; ++t) {
        if (layer == 0 && w == 0 && ln < 4) {   // x-gates prefetch (pre-poll)
            #pragma unroll
            for (int g = 0; g < 4; ++g)
                add4[g] = xg[(size_t)t * G4 + g * HID + u0 + ln];
        }

        // ---- acquire h vectors (block-rotated unit assignment) ----
        const int p4 = 4 * ((tid + b) & 255);
        bool doneP = (t == 0), doneI = (layer == 0);
        u64 vp0 = 0, vp1 = 0, vp2 = 0, vp3 = 0;
        u64 vi0 = 0, vi1 = 0, vi2 = 0, vi3 = 0;
        const u64 tagP = (u64)(unsigned)t;          // hbP[t-1] carries tag t
        const u64 tagI = (u64)(unsigned)(t + 1);    // hbI[t]   carries tag t+1
        const u64* pp = hbP + (size_t)(t - 1) * HID + p4;
        const u64* pi = hbI + (size_t)t * HID + p4;
        int guard = 0;
        for (;;) {
            if (!doneP) {
                vp0 = __hip_atomic_load(pp + 0, __ATOMIC_RELAXED, __HIP_MEMORY_SCOPE_AGENT);
                if ((vp0 >> 32) == tagP) {   // sentinel hit: quad published together
                    vp1 = __hip_atomic_load(pp + 1, __ATOMIC_RELAXED, __HIP_MEMORY_SCOPE_AGENT);
                    vp2 = __hip_atomic_load(pp + 2, __ATOMIC_RELAXED, __HIP_MEMORY_SCOPE_AGENT);
                    vp3 = __hip_atomic_load(pp + 3, __ATOMIC_RELAXED, __HIP_MEMORY_SCOPE_AGENT);
                    doneP = (vp1 >> 32) == tagP && (vp2 >> 32) == tagP &&
                            (vp3 >> 32) == tagP;
                }
            }
            if (!doneI) {
                vi0 = __hip_atomic_load(pi + 0, __ATOMIC_RELAXED, __HIP_MEMORY_SCOPE_AGENT);
                if ((vi0 >> 32) == tagI) {
                    vi1 = __hip_atomic_load(pi + 1, __ATOMIC_RELAXED, __HIP_MEMORY_SCOPE_AGENT);
                    vi2 = __hip_atomic_load(pi + 2, __ATOMIC_RELAXED, __HIP_MEMORY_SCOPE_AGENT);
                    vi3 = __hip_atomic_load(pi + 3, __ATOMIC_RELAXED, __HIP_MEMORY_SCOPE_AGENT);
                    doneI = (vi1 >> 32) == tagI && (vi2 >> 32) == tagI &&
                            (vi3 >> 32) == tagI;
                }
            }
            if (doneP && doneI) break;
            if (++guard > (1 << 22)) break;   // anti-hang bailout (unreached when healthy)
            __builtin_amdgcn_s_sleep(1);      // ~64cy backoff: cut straggler spin pressure
        }
        if (t == 0)
            *(float4*)&hprev_lds[p4] = make_float4(0.f, 0.f, 0.f, 0.f);
        else
            *(float4*)&hprev_lds[p4] = make_float4(
                __uint_as_float((unsigned)vp0), __uint_as_float((unsigned)vp1),
                __uint_as_float((unsigned)vp2), __uint_as_float((unsigned)vp3));
        if (layer > 0)
            *(float4*)&hin_lds[p4] = make_float4(
                __uint_as_float((unsigned)vi0), __uint_as_float((unsigned)vi1),
                __uint_as_float((unsigned)vi2), __uint_as_float((unsigned)vi3));
        __syncthreads();   // (1) h vectors staged

        // ---- matvec: 4 gate rows x 32 cols, weights in regs, h from LDS ----
        const float* hsrc = (inHalf ? hin_lds : hprev_lds) + 4 * q;
        float a0 = 0.f, a1 = 0.f, a2 = 0.f, a3 = 0.f;
        #pragma unroll
        for (int j = 0; j < 8; ++j) {
            const float4 hv = *(const float4*)(hsrc + 128 * j);
            a0 += Wv[0][j].x * hv.x + Wv[0][j].y * hv.y + Wv[0][j].z * hv.z + Wv[0][j].w * hv.w;
            a1 += Wv[1][j].x * hv.x + Wv[1][j].y * hv.y + Wv[1][j].z * hv.z + Wv[1][j].w * hv.w;
            a2 += Wv[2][j].x * hv.x + Wv[2][j].y * hv.y + Wv[2][j].z * hv.z + Wv[2][j].w * hv.w;
            a3 += Wv[3][j].x * hv.x + Wv[3][j].y * hv.y + Wv[3][j].z * hv.z + Wv[3][j].w * hv.w;
        }
        // 64-lane butterfly: sums ih-partials (lanes<32) + hh-partials (>=32)
        #pragma unroll
        for (int off = 1; off < 64; off <<= 1) {
            a0 += __shfl_xor(a0, off, 64);
            a1 += __shfl_xor(a1, off, 64);
            a2 += __shfl_xor(a2, off, 64);
            a3 += __shfl_xor(a3, off, 64);
        }
        if (ln == 0) {
            gsum[w][0] = a0; gsum[w][1] = a1; gsum[w][2] = a2; gsum[w][3] = a3;
        }
        __syncthreads();   // (2) gate sums exchanged; LDS safe to overwrite next iter

        // ---- wave 0 lanes 0..3: elementwise + COALESCED quad publish ----
        if (w == 0 && ln < 4) {
            const float i_ = sig_(gsum[ln][0] + add4[0]);
            const float f_ = sig_(gsum[ln][1] + add4[1]);
            const float g_ = tanhf(gsum[ln][2] + add4[2]);
            const float o_ = sig_(gsum[ln][3] + add4[3]);
            c = f_ * c + i_ * g_;
            const float h = o_ * tanhf(c);
            if (layer == 2) hs2[(size_t)t * HID + u0 + ln] = h;
            const u64 pv = (((u64)(unsigned)(t + 1)) << 32) |
                           (u64)__float_as_uint(h);
            __hip_atomic_store(hbP + (size_t)t * HID + u0 + ln, pv,
                               __ATOMIC_RELAXED, __HIP_MEMORY_SCOPE_AGENT);
        }
        // Next iteration's poll gates every consumer on this publish; gsum is
        // rewritten only after the next barrier(1)+matvec, so no extra barrier.
    }
}

// ---------------------------------------------------------------------------
extern "C" void kernel_launch(void* const* d_in, const int* in_sizes, int n_in,
                              void* d_out, int out_size, void* d_ws, size_t ws_size,
                              hipStream_t stream)
{
    (void)in_sizes; (void)n_in; (void)out_size; (void)ws_size;

    const float* pose = (const float*)d_in[0];
    const float* Wih0 = (const float*)d_in[1];
    const float* Whh0 = (const float*)d_in[2];
    const float* bih0 = (const float*)d_in[3];
    const float* bhh0 = (const float*)d_in[4];
    const float* Wih1 = (const float*)d_in[5];
    const float* Whh1 = (const float*)d_in[6];
    const float* bih1 = (const float*)d_in[7];
    const float* bhh1 = (const float*)d_in[8];
    const float* Wih2 = (const float*)d_in[9];
    const float* Whh2 = (const float*)d_in[10];
    const float* bih2 = (const float*)d_in[11];
    const float* bhh2 = (const float*)d_in[12];
    const float* Wout = (const float*)d_in[13];
    float* out = (float*)d_out;

    // Workspace: hbuf0|hbuf1|hbuf2 (3 x 4 MB tagged u64) | xg (8 MB) | hs2 (2 MB)
    char* ws = (char*)d_ws;
    const size_t HB = (size_t)TT * HID * sizeof(u64);
    u64* hbuf0 = (u64*)ws;
    u64* hbuf1 = (u64*)(ws + HB);
    u64* hbuf2 = (u64*)(ws + 2 * HB);
    float* xg  = (float*)(ws + 3 * HB);
    float* hs2 = (float*)(ws + 3 * HB + (size_t)TT * G4 * sizeof(float));

    hipMemsetAsync(hbuf0, 0, 3 * HB, stream);

    const dim3 blk(256);
    // layer-0 x-gates: [512,85] x [85,4096]^T (+ both biases)
    gemm_nt<<<dim3(G4 / 64, TT / 64), blk, 0, stream>>>(
        pose, Wih0, bih0, bhh0, xg, TT, G4, INDIM);
    // fused pipelined 3-layer scan
    lstm_fused<<<dim3(768), blk, 0, stream>>>(
        xg, Whh0, Wih1, Whh1, bih1, bhh1, Wih2, Whh2, bih2, bhh2,
        hbuf0, hbuf1, hbuf2, hs2);
    // output projection: [512,1024] x [1024,20670]^T
    gemm_nt<<<dim3((NOUT + 63) / 64, TT / 64), blk, 0, stream>>>(
        hs2, Wout, nullptr, nullptr, out, TT, NOUT, HID);
}